// Round 4
// baseline (565.904 us; speedup 1.0000x reference)
//
#include <hip/hip_runtime.h>

#define NTOK   131072
#define KCODES 1024
#define DIM    64
#define BM     128

#define LOSS_OFF (NTOK * DIM)        // 8388608
#define IDX_OFF  (LOSS_OFF + 1)      // 8388609

#define EPS_U 6e-5f                  // u-metric gap threshold (d-gap = 2u)

typedef __attribute__((ext_vector_type(8))) short bf16x8;
typedef __attribute__((ext_vector_type(4))) float f32x4;
typedef __attribute__((ext_vector_type(4))) unsigned short ush4;

__device__ inline unsigned short bf16rtn(float x) {
    unsigned u = __float_as_uint(x);
    return (unsigned short)((u + 0x7fffu + ((u >> 16) & 1u)) >> 16);
}

// ---------------------------------------------- K0a: clear flag bitmap
__global__ __launch_bounds__(256) void clear_kernel(unsigned* __restrict__ bm) {
    int i = blockIdx.x * 256 + threadIdx.x;
    if (i < 4096) bm[i] = 0u;
}

// ---------------------------------------------- K0b: e_sq (+ half)
__global__ __launch_bounds__(256) void esq_kernel(const float* __restrict__ E,
                                                  float* __restrict__ esq,
                                                  float* __restrict__ esqh) {
    int c = blockIdx.x * blockDim.x + threadIdx.x;
    if (c < KCODES) {
        const float4* row = (const float4*)(E + c * DIM);
        float s = 0.f;
        #pragma unroll
        for (int i = 0; i < DIM / 4; ++i) {
            float4 v = row[i];
            s += v.x * v.x + v.y * v.y + v.z * v.z + v.w * v.w;
        }
        esq[c] = s;
        esqh[c] = 0.5f * s;          // exact
    }
}

// ---------------------------------------------- K0c: split E -> bf16 hi|lo
__global__ __launch_bounds__(256) void bsplit_kernel(const float* __restrict__ E,
                                                     unsigned short* __restrict__ B) {
    int id = blockIdx.x * 256 + threadIdx.x;   // 65536 = 1024 x 64
    int c = id >> 6, k = id & 63;
    float x = E[id];
    unsigned short h = bf16rtn(x);
    float hf = __uint_as_float(((unsigned)h) << 16);
    unsigned short lo = bf16rtn(x - hf);
    B[c * 128 + k]      = h;
    B[c * 128 + 64 + k] = lo;
}

// ------------------------------------------------- K1: MFMA distances + argmin
// Per block: 128 tokens x ALL 1024 codes (8 n-tiles of 128). K=192 bf16
// (hh, hl, lh split terms). A(z) converted to hi|lo in-kernel -> LDS 32KB;
// B staged per n-tile from pre-split global (T14 issue-early/write-late).
// Tracks per-token (best, second, idx) on u = esq/2 - dot; near-ties flagged.
__global__ __launch_bounds__(256) void mfma_argmin_kernel(
    const float* __restrict__ z, const unsigned short* __restrict__ Bsp,
    const float* __restrict__ esqh_g, float* __restrict__ idx_out,
    unsigned* __restrict__ bitmap) {
    __shared__ __align__(16) unsigned short As[16384];   // 32KB [128 tok][128 k]
    __shared__ __align__(16) unsigned short Bs[16384];   // 32KB [128 code][128 k]
    __shared__ __align__(16) float esqh_s[KCODES];       // 4KB

    char* AsB = (char*)As;
    char* BsB = (char*)Bs;

    const int t = threadIdx.x;
    const int l = t & 63;
    const int w = t >> 6;            // wave 0..3, owns 32 token-rows
    const int wm = w * 32;
    const int lan15 = l & 15;
    const int kp16 = (l >> 4) * 16;  // k-group byte offset within fragment
    const int row0 = blockIdx.x * BM;

    // stage esq_half
    #pragma unroll
    for (int p = 0; p < 4; ++p) esqh_s[p * 256 + t] = esqh_g[p * 256 + t];

    // ---- prologue: load z tile + B tile 0, convert/write A, write B ----
    float4 av[8];
    {
        const float4* zg = (const float4*)(z + (size_t)row0 * DIM);
        #pragma unroll
        for (int p = 0; p < 8; ++p) av[p] = zg[p * 256 + t];
    }
    uint4 pv[8];
    {
        const uint4* bg = (const uint4*)Bsp;
        #pragma unroll
        for (int p = 0; p < 8; ++p) pv[p] = bg[p * 256 + t];
    }
    #pragma unroll
    for (int p = 0; p < 8; ++p) {
        int li = p * 256 + t;
        int r = li >> 4, q = li & 15;          // token row, float4 chunk
        float xs[4] = {av[p].x, av[p].y, av[p].z, av[p].w};
        ush4 hv, lv;
        #pragma unroll
        for (int j = 0; j < 4; ++j) {
            unsigned short h = bf16rtn(xs[j]);
            float hf = __uint_as_float(((unsigned)h) << 16);
            hv[j] = h;
            lv[j] = bf16rtn(xs[j] - hf);
        }
        int rx = (r & 7) << 4;
        *(ush4*)(AsB + r * 256 + ((q * 8) ^ rx))       = hv;
        *(ush4*)(AsB + r * 256 + ((128 + q * 8) ^ rx)) = lv;
    }
    #pragma unroll
    for (int p = 0; p < 8; ++p) {
        int li = p * 256 + t;
        int r = li >> 4, q = li & 15;
        *(uint4*)(BsB + r * 256 + ((q * 16) ^ ((r & 7) << 4))) = pv[p];
    }
    __syncthreads();

    // fragment base addresses
    int rb[2], rx[2];
    #pragma unroll
    for (int fr = 0; fr < 2; ++fr) {
        int row = wm + fr * 16 + lan15;
        rb[fr] = row * 256;
        rx[fr] = (row & 7) << 4;
    }
    int cb[8], cx[8];
    #pragma unroll
    for (int fc = 0; fc < 8; ++fc) {
        int col = fc * 16 + lan15;
        cb[fc] = col * 256;
        cx[fc] = (col & 7) << 4;
    }
    const int ka[6] = {0, 64, 0, 64, 128, 192};   // A: hi,hi,hi,hi,lo,lo
    const int kb[6] = {0, 64, 128, 192, 0, 64};   // B: hi,hi,lo,lo,hi,hi

    float best[8], second[8];
    int   bidx[8];
    #pragma unroll
    for (int s = 0; s < 8; ++s) { best[s] = 3.4e38f; second[s] = 3.4e38f; bidx[s] = 0; }

    for (int ct = 0; ct < 8; ++ct) {             // ascending code tiles
        uint4 pv2[8];
        if (ct < 7) {                            // issue-early next B tile
            const uint4* bg2 = (const uint4*)Bsp + (size_t)(ct + 1) * 2048;
            #pragma unroll
            for (int p = 0; p < 8; ++p) pv2[p] = bg2[p * 256 + t];
        }

        f32x4 acc[2][8];
        #pragma unroll
        for (int fr = 0; fr < 2; ++fr)
            #pragma unroll
            for (int fc = 0; fc < 8; ++fc)
                acc[fr][fc] = (f32x4){0.f, 0.f, 0.f, 0.f};

        #pragma unroll
        for (int ks = 0; ks < 6; ++ks) {
            bf16x8 af[2], bfr[8];
            #pragma unroll
            for (int fr = 0; fr < 2; ++fr)
                af[fr] = *(const bf16x8*)(AsB + rb[fr] + ((ka[ks] + kp16) ^ rx[fr]));
            #pragma unroll
            for (int fc = 0; fc < 8; ++fc)
                bfr[fc] = *(const bf16x8*)(BsB + cb[fc] + ((kb[ks] + kp16) ^ cx[fc]));
            #pragma unroll
            for (int fr = 0; fr < 2; ++fr)
                #pragma unroll
                for (int fc = 0; fc < 8; ++fc)
                    acc[fr][fc] = __builtin_amdgcn_mfma_f32_16x16x32_bf16(
                        af[fr], bfr[fc], acc[fr][fc], 0, 0, 0);
        }

        // epilogue: u = esq/2 - dot; running (best, second, idx), cols ascending
        #pragma unroll
        for (int fc = 0; fc < 8; ++fc) {
            float eh = esqh_s[ct * 128 + fc * 16 + lan15];
            int col = ct * 128 + fc * 16 + lan15;
            #pragma unroll
            for (int fr = 0; fr < 2; ++fr) {
                #pragma unroll
                for (int r = 0; r < 4; ++r) {
                    float u = eh - acc[fr][fc][r];
                    int s = fr * 4 + r;
                    if (u < best[s]) { second[s] = best[s]; best[s] = u; bidx[s] = col; }
                    else if (u < second[s]) second[s] = u;
                }
            }
        }
        __syncthreads();                          // done reading Bs
        if (ct < 7) {                             // write-late staging
            #pragma unroll
            for (int p = 0; p < 8; ++p) {
                int li = p * 256 + t;
                int r = li >> 4, q = li & 15;
                *(uint4*)(BsB + r * 256 + ((q * 16) ^ ((r & 7) << 4))) = pv2[p];
            }
        }
        __syncthreads();
    }

    // cross-lane reduce within 16-lane groups (same row set); ties -> low idx
    #pragma unroll
    for (int s = 0; s < 8; ++s) {
        float b = best[s], sc = second[s];
        int bi = bidx[s];
        #pragma unroll
        for (int off = 1; off <= 8; off <<= 1) {
            float ob = __shfl_xor(b, off);
            float os = __shfl_xor(sc, off);
            int   oi = __shfl_xor(bi, off);
            float mx = fmaxf(b, ob);
            sc = fminf(fminf(sc, os), mx);
            if (ob < b) { b = ob; bi = oi; }
            else if (ob == b) bi = min(bi, oi);
        }
        if (lan15 == 0) {
            int row = wm + (s >> 2) * 16 + (l >> 4) * 4 + (s & 3);
            int gid = row0 + row;
            idx_out[gid] = (float)bi;
            if (sc - b <= EPS_U)
                atomicOr(&bitmap[gid >> 5], 1u << (gid & 31));
        }
    }
}

// ---------------------- K1b: exact recompute for flagged (near-tie) tokens
// Replicates the R1-R3 VALU kernel's arithmetic exactly: sequential fused
// FMA chains, d = (zsq - 2*acc) + esq, strict < with lexicographic ties.
__global__ __launch_bounds__(256) void fallback_kernel(
    const float* __restrict__ z, const float* __restrict__ E,
    const float* __restrict__ esq_g, float* __restrict__ idx_out,
    const unsigned* __restrict__ bitmap) {
    __shared__ float zl[4][64];
    const int t = threadIdx.x;
    const int l = t & 63;
    const int w = t >> 6;
    const int wid = blockIdx.x * 4 + w;          // 1024 waves total

    for (int tok = wid; tok < NTOK; tok += 1024) {
        if (!(bitmap[tok >> 5] & (1u << (tok & 31)))) continue;
        zl[w][l] = z[(size_t)tok * 64 + l];
        float zq = 0.f;
        for (int k = 0; k < 64; ++k) { float v = zl[w][k]; zq += v * v; }
        float best = 3.4e38f;
        int bi = 0;
        for (int j = 0; j < 16; ++j) {
            int c = j * 64 + l;
            const float4* e4 = (const float4*)(E + (size_t)c * 64);
            float acc = 0.f;
            #pragma unroll 4
            for (int q = 0; q < 16; ++q) {
                float4 ev = e4[q];
                acc += zl[w][q * 4 + 0] * ev.x;
                acc += zl[w][q * 4 + 1] * ev.y;
                acc += zl[w][q * 4 + 2] * ev.z;
                acc += zl[w][q * 4 + 3] * ev.w;
            }
            float d = (zq - 2.0f * acc) + esq_g[c];
            if (d < best) { best = d; bi = c; }
        }
        for (int off = 32; off >= 1; off >>= 1) {
            float ob = __shfl_xor(best, off);
            int   oi = __shfl_xor(bi, off);
            if (ob < best || (ob == best && oi < bi)) { best = ob; bi = oi; }
        }
        if (l == 0) idx_out[tok] = (float)bi;
    }
}

// ------------------------------- K2: gather z_q, write out0, loss partials
__global__ __launch_bounds__(256) void gather_kernel(
    const float* __restrict__ z, const float* __restrict__ E,
    const float* __restrict__ idx_f, float* __restrict__ out0,
    float* __restrict__ partials) {
    __shared__ float red[4];
    const int t = threadIdx.x;
    const int token = blockIdx.x * 16 + (t >> 4);
    const int part  = t & 15;

    int id = (int)idx_f[token];
    const float4* z4 = (const float4*)z;
    const float4* E4 = (const float4*)E;
    float4 zv = z4[(size_t)token * 16 + part];
    float4 ev = E4[(size_t)id * 16 + part];

    float dx = ev.x - zv.x, dy = ev.y - zv.y, dz = ev.z - zv.z, dw = ev.w - zv.w;
    float4 o;
    o.x = zv.x + dx; o.y = zv.y + dy; o.z = zv.z + dz; o.w = zv.w + dw;
    ((float4*)out0)[(size_t)token * 16 + part] = o;

    float ls = dx * dx + dy * dy + dz * dz + dw * dw;
    #pragma unroll
    for (int off = 32; off >= 1; off >>= 1) ls += __shfl_xor(ls, off);
    if ((t & 63) == 0) red[t >> 6] = ls;
    __syncthreads();
    if (t == 0) partials[blockIdx.x] = red[0] + red[1] + red[2] + red[3];
}

// ------------------------------------------------------- K3: final loss
__global__ __launch_bounds__(256) void loss_kernel(
    const float* __restrict__ partials, int n, float* __restrict__ loss_out) {
    __shared__ float red[4];
    const int t = threadIdx.x;
    float s = 0.f;
    for (int i = t; i < n; i += 256) s += partials[i];
    #pragma unroll
    for (int off = 32; off >= 1; off >>= 1) s += __shfl_xor(s, off);
    if ((t & 63) == 0) red[t >> 6] = s;
    __syncthreads();
    if (t == 0) {
        float tot = red[0] + red[1] + red[2] + red[3];
        float m = tot / (float)(NTOK * DIM);
        loss_out[0] = m + 0.25f * m;
    }
}

extern "C" void kernel_launch(void* const* d_in, const int* in_sizes, int n_in,
                              void* d_out, int out_size, void* d_ws, size_t ws_size,
                              hipStream_t stream) {
    const float* z = (const float*)d_in[0];       // [131072, 64] f32
    const float* E = (const float*)d_in[1];       // [1024, 64] f32
    float* out = (float*)d_out;

    char* wsb = (char*)d_ws;
    float*          esq      = (float*)(wsb);             // 4 KB
    float*          esqh     = (float*)(wsb + 4096);      // 4 KB
    float*          partials = (float*)(wsb + 8192);      // 32 KB
    unsigned*       bitmap   = (unsigned*)(wsb + 40960);  // 16 KB
    unsigned short* Bsp      = (unsigned short*)(wsb + 57344); // 256 KB

    clear_kernel<<<16, 256, 0, stream>>>(bitmap);
    esq_kernel<<<4, 256, 0, stream>>>(E, esq, esqh);
    bsplit_kernel<<<256, 256, 0, stream>>>(E, Bsp);
    mfma_argmin_kernel<<<NTOK / BM, 256, 0, stream>>>(z, Bsp, esqh,
                                                      out + IDX_OFF, bitmap);
    fallback_kernel<<<256, 256, 0, stream>>>(z, E, esq, out + IDX_OFF, bitmap);
    gather_kernel<<<NTOK / 16, 256, 0, stream>>>(z, E, out + IDX_OFF, out, partials);
    loss_kernel<<<1, 256, 0, stream>>>(partials, NTOK / 16, out + LOSS_OFF);
}

// Round 5
// 235.699 us; speedup vs baseline: 2.4010x; 2.4010x over previous
//
#include <hip/hip_runtime.h>

#define NTOK   131072
#define KCODES 1024
#define DIM    64
#define BM     128

#define LOSS_OFF (NTOK * DIM)        // 8388608
#define IDX_OFF  (LOSS_OFF + 1)      // 8388609

#define EPS_U 6e-5f                  // u-metric gap threshold (d-gap = 2u)

typedef __attribute__((ext_vector_type(8))) short bf16x8;
typedef __attribute__((ext_vector_type(4))) float f32x4;
typedef __attribute__((ext_vector_type(4))) unsigned short ush4;

__device__ inline unsigned short bf16rtn(float x) {
    unsigned u = __float_as_uint(x);
    return (unsigned short)((u + 0x7fffu + ((u >> 16) & 1u)) >> 16);
}

// ---------------------------------------------- K0a: clear worklist counter
__global__ __launch_bounds__(64) void clear_kernel(int* __restrict__ cnt) {
    if (threadIdx.x == 0) cnt[0] = 0;
}

// ---------------------------------------------- K0b: e_sq (+ half)
__global__ __launch_bounds__(256) void esq_kernel(const float* __restrict__ E,
                                                  float* __restrict__ esq,
                                                  float* __restrict__ esqh) {
    int c = blockIdx.x * blockDim.x + threadIdx.x;
    if (c < KCODES) {
        const float4* row = (const float4*)(E + c * DIM);
        float s = 0.f;
        #pragma unroll
        for (int i = 0; i < DIM / 4; ++i) {
            float4 v = row[i];
            s += v.x * v.x + v.y * v.y + v.z * v.z + v.w * v.w;
        }
        esq[c] = s;
        esqh[c] = 0.5f * s;          // exact
    }
}

// ---------------------------------------------- K0c: split E -> bf16 hi|lo
__global__ __launch_bounds__(256) void bsplit_kernel(const float* __restrict__ E,
                                                     unsigned short* __restrict__ B) {
    int id = blockIdx.x * 256 + threadIdx.x;   // 65536 = 1024 x 64
    int c = id >> 6, k = id & 63;
    float x = E[id];
    unsigned short h = bf16rtn(x);
    float hf = __uint_as_float(((unsigned)h) << 16);
    unsigned short lo = bf16rtn(x - hf);
    B[c * 128 + k]      = h;
    B[c * 128 + 64 + k] = lo;
}

// ------------------------------------------------- K1: MFMA distances + argmin
// Per block: 128 tokens x ALL 1024 codes (8 n-tiles of 128). K=192 bf16
// (hh, hl, lh split terms). Tracks per-token (best, second, idx) on
// u = esq/2 - dot; near-ties appended to a worklist for exact recompute.
__global__ __launch_bounds__(256) void mfma_argmin_kernel(
    const float* __restrict__ z, const unsigned short* __restrict__ Bsp,
    const float* __restrict__ esqh_g, float* __restrict__ idx_out,
    int* __restrict__ cnt, int* __restrict__ wl) {
    __shared__ __align__(16) unsigned short As[16384];   // 32KB [128 tok][128 k]
    __shared__ __align__(16) unsigned short Bs[16384];   // 32KB [128 code][128 k]
    __shared__ __align__(16) float esqh_s[KCODES];       // 4KB

    char* AsB = (char*)As;
    char* BsB = (char*)Bs;

    const int t = threadIdx.x;
    const int l = t & 63;
    const int w = t >> 6;            // wave 0..3, owns 32 token-rows
    const int wm = w * 32;
    const int lan15 = l & 15;
    const int kp16 = (l >> 4) * 16;  // k-group byte offset within fragment
    const int row0 = blockIdx.x * BM;

    // stage esq_half
    #pragma unroll
    for (int p = 0; p < 4; ++p) esqh_s[p * 256 + t] = esqh_g[p * 256 + t];

    // ---- prologue: load z tile + B tile 0, convert/write A, write B ----
    float4 av[8];
    {
        const float4* zg = (const float4*)(z + (size_t)row0 * DIM);
        #pragma unroll
        for (int p = 0; p < 8; ++p) av[p] = zg[p * 256 + t];
    }
    uint4 pv[8];
    {
        const uint4* bg = (const uint4*)Bsp;
        #pragma unroll
        for (int p = 0; p < 8; ++p) pv[p] = bg[p * 256 + t];
    }
    #pragma unroll
    for (int p = 0; p < 8; ++p) {
        int li = p * 256 + t;
        int r = li >> 4, q = li & 15;          // token row, float4 chunk
        float xs[4] = {av[p].x, av[p].y, av[p].z, av[p].w};
        ush4 hv, lv;
        #pragma unroll
        for (int j = 0; j < 4; ++j) {
            unsigned short h = bf16rtn(xs[j]);
            float hf = __uint_as_float(((unsigned)h) << 16);
            hv[j] = h;
            lv[j] = bf16rtn(xs[j] - hf);
        }
        int rx = (r & 7) << 4;
        *(ush4*)(AsB + r * 256 + ((q * 8) ^ rx))       = hv;
        *(ush4*)(AsB + r * 256 + ((128 + q * 8) ^ rx)) = lv;
    }
    #pragma unroll
    for (int p = 0; p < 8; ++p) {
        int li = p * 256 + t;
        int r = li >> 4, q = li & 15;
        *(uint4*)(BsB + r * 256 + ((q * 16) ^ ((r & 7) << 4))) = pv[p];
    }
    __syncthreads();

    // fragment base addresses
    int rb[2], rx[2];
    #pragma unroll
    for (int fr = 0; fr < 2; ++fr) {
        int row = wm + fr * 16 + lan15;
        rb[fr] = row * 256;
        rx[fr] = (row & 7) << 4;
    }
    int cb[8], cx[8];
    #pragma unroll
    for (int fc = 0; fc < 8; ++fc) {
        int col = fc * 16 + lan15;
        cb[fc] = col * 256;
        cx[fc] = (col & 7) << 4;
    }
    const int ka[6] = {0, 64, 0, 64, 128, 192};   // A: hi,hi,hi,hi,lo,lo
    const int kb[6] = {0, 64, 128, 192, 0, 64};   // B: hi,hi,lo,lo,hi,hi

    float best[8], second[8];
    int   bidx[8];
    #pragma unroll
    for (int s = 0; s < 8; ++s) { best[s] = 3.4e38f; second[s] = 3.4e38f; bidx[s] = 0; }

    for (int ct = 0; ct < 8; ++ct) {             // ascending code tiles
        uint4 pv2[8];
        if (ct < 7) {                            // issue-early next B tile
            const uint4* bg2 = (const uint4*)Bsp + (size_t)(ct + 1) * 2048;
            #pragma unroll
            for (int p = 0; p < 8; ++p) pv2[p] = bg2[p * 256 + t];
        }

        f32x4 acc[2][8];
        #pragma unroll
        for (int fr = 0; fr < 2; ++fr)
            #pragma unroll
            for (int fc = 0; fc < 8; ++fc)
                acc[fr][fc] = (f32x4){0.f, 0.f, 0.f, 0.f};

        #pragma unroll
        for (int ks = 0; ks < 6; ++ks) {
            bf16x8 af[2], bfr[8];
            #pragma unroll
            for (int fr = 0; fr < 2; ++fr)
                af[fr] = *(const bf16x8*)(AsB + rb[fr] + ((ka[ks] + kp16) ^ rx[fr]));
            #pragma unroll
            for (int fc = 0; fc < 8; ++fc)
                bfr[fc] = *(const bf16x8*)(BsB + cb[fc] + ((kb[ks] + kp16) ^ cx[fc]));
            #pragma unroll
            for (int fr = 0; fr < 2; ++fr)
                #pragma unroll
                for (int fc = 0; fc < 8; ++fc)
                    acc[fr][fc] = __builtin_amdgcn_mfma_f32_16x16x32_bf16(
                        af[fr], bfr[fc], acc[fr][fc], 0, 0, 0);
        }

        // epilogue: u = esq/2 - dot; branchless (best, second, idx) update
        #pragma unroll
        for (int fc = 0; fc < 8; ++fc) {
            float eh = esqh_s[ct * 128 + fc * 16 + lan15];
            int col = ct * 128 + fc * 16 + lan15;
            #pragma unroll
            for (int fr = 0; fr < 2; ++fr) {
                #pragma unroll
                for (int r = 0; r < 4; ++r) {
                    float u = eh - acc[fr][fc][r];
                    int s = fr * 4 + r;
                    second[s] = fminf(second[s], fmaxf(u, best[s]));
                    bool lt = u < best[s];
                    bidx[s] = lt ? col : bidx[s];
                    best[s] = fminf(u, best[s]);
                }
            }
        }
        __syncthreads();                          // done reading Bs
        if (ct < 7) {                             // write-late staging
            #pragma unroll
            for (int p = 0; p < 8; ++p) {
                int li = p * 256 + t;
                int r = li >> 4, q = li & 15;
                *(uint4*)(BsB + r * 256 + ((q * 16) ^ ((r & 7) << 4))) = pv2[p];
            }
        }
        __syncthreads();
    }

    // cross-lane reduce within 16-lane groups (same row set); ties -> low idx
    #pragma unroll
    for (int s = 0; s < 8; ++s) {
        float b = best[s], sc = second[s];
        int bi = bidx[s];
        #pragma unroll
        for (int off = 1; off <= 8; off <<= 1) {
            float ob = __shfl_xor(b, off);
            float os = __shfl_xor(sc, off);
            int   oi = __shfl_xor(bi, off);
            float mx = fmaxf(b, ob);
            sc = fminf(fminf(sc, os), mx);
            if (ob < b) { b = ob; bi = oi; }
            else if (ob == b) bi = min(bi, oi);
        }
        if (lan15 == 0) {
            int row = wm + (s >> 2) * 16 + (l >> 4) * 4 + (s & 3);
            int gid = row0 + row;
            idx_out[gid] = (float)bi;
            if (sc - b <= EPS_U) {
                int slot = atomicAdd(cnt, 1);
                if (slot < NTOK) wl[slot] = gid;
            }
        }
    }
}

// ---------------------- K1b: exact recompute for worklisted (near-tie) tokens
// Chunk of 16 tokens per block iteration; E staged in 128-code tiles with the
// R2 kernel's exact transpose/read pattern; per (token,code) arithmetic is the
// validated R1/R2 chain: sequential k FMA, d=(zq-2*acc)+esq, strict <,
// lexicographic 16-lane reduce.
__global__ __launch_bounds__(256) void fallback_kernel(
    const float* __restrict__ z, const float* __restrict__ E,
    const float* __restrict__ esq_g, float* __restrict__ idx_out,
    const int* __restrict__ wl, const int* __restrict__ cnt_p) {
    __shared__ __align__(16) float es[DIM][128];   // 32KB [k][code]
    __shared__ __align__(16) float zl[16][72];     // padded: conflict-free a-reads
    __shared__ float zqs[16];

    const int t = threadIdx.x;
    const int tg = t >> 4;           // token slot 0..15
    const int cs = t & 15;           // code slice (8 codes per tile)
    const int cnt = min(*cnt_p, NTOK);

    for (int chunk = blockIdx.x; chunk * 16 < cnt; chunk += 256) {
        const int base = chunk * 16;
        const int nval = min(16, cnt - base);
        const int tok = wl[base + (tg < nval ? tg : 0)];
        {   // stage z rows (slot = t>>4, q = t&15): coalesced per row
            float4 v = ((const float4*)z)[(size_t)tok * 16 + cs];
            *(float4*)&zl[tg][cs * 4] = v;
        }
        __syncthreads();
        if (t < 16) {                // zq per slot, sequential k (as R1)
            float s = 0.f;
            for (int k = 0; k < DIM; ++k) { float v = zl[t][k]; s += v * v; }
            zqs[t] = s;
        }
        __syncthreads();
        const float zq = zqs[tg];

        float best = 3.4e38f;
        int bi = 0;
        for (int tile = 0; tile < 8; ++tile) {   // ascending code tiles
            const float4* eg = (const float4*)(E + (size_t)tile * 128 * DIM);
            #pragma unroll
            for (int p = 0; p < 8; ++p) {        // R2 staging pattern verbatim
                int li = p * 256 + t;
                int c = li & 127, k4 = li >> 7;
                float4 v = eg[c * 16 + k4];
                es[k4 * 4 + 0][c] = v.x;
                es[k4 * 4 + 1][c] = v.y;
                es[k4 * 4 + 2][c] = v.z;
                es[k4 * 4 + 3][c] = v.w;
            }
            __syncthreads();

            float acc[8];
            #pragma unroll
            for (int n = 0; n < 8; ++n) acc[n] = 0.f;
            #pragma unroll 8
            for (int k = 0; k < DIM; ++k) {      // sequential fp32 FMA over K
                float a = zl[tg][k];
                float4 b0 = *(const float4*)&es[k][cs * 8 + 0];
                float4 b1 = *(const float4*)&es[k][cs * 8 + 4];
                float b[8] = {b0.x, b0.y, b0.z, b0.w, b1.x, b1.y, b1.z, b1.w};
                #pragma unroll
                for (int n = 0; n < 8; ++n) acc[n] += a * b[n];
            }
            #pragma unroll
            for (int n = 0; n < 8; ++n) {        // ascending code index, strict <
                int c = tile * 128 + cs * 8 + n;
                float d = (zq - 2.0f * acc[n]) + esq_g[c];
                if (d < best) { best = d; bi = c; }
            }
            __syncthreads();
        }
        // lexicographic reduce over the 16 lanes of this token group
        #pragma unroll
        for (int off = 1; off <= 8; off <<= 1) {
            float ob = __shfl_xor(best, off);
            int   oi = __shfl_xor(bi, off);
            if (ob < best || (ob == best && oi < bi)) { best = ob; bi = oi; }
        }
        if (cs == 0 && tg < nval) idx_out[tok] = (float)bi;
        __syncthreads();             // zl/es reused next chunk
    }
}

// ------------------------------- K2: gather z_q, write out0, loss partials
__global__ __launch_bounds__(256) void gather_kernel(
    const float* __restrict__ z, const float* __restrict__ E,
    const float* __restrict__ idx_f, float* __restrict__ out0,
    float* __restrict__ partials) {
    __shared__ float red[4];
    const int t = threadIdx.x;
    const int token = blockIdx.x * 16 + (t >> 4);
    const int part  = t & 15;

    int id = (int)idx_f[token];
    const float4* z4 = (const float4*)z;
    const float4* E4 = (const float4*)E;
    float4 zv = z4[(size_t)token * 16 + part];
    float4 ev = E4[(size_t)id * 16 + part];

    float dx = ev.x - zv.x, dy = ev.y - zv.y, dz = ev.z - zv.z, dw = ev.w - zv.w;
    float4 o;
    o.x = zv.x + dx; o.y = zv.y + dy; o.z = zv.z + dz; o.w = zv.w + dw;
    ((float4*)out0)[(size_t)token * 16 + part] = o;

    float ls = dx * dx + dy * dy + dz * dz + dw * dw;
    #pragma unroll
    for (int off = 32; off >= 1; off >>= 1) ls += __shfl_xor(ls, off);
    if ((t & 63) == 0) red[t >> 6] = ls;
    __syncthreads();
    if (t == 0) partials[blockIdx.x] = red[0] + red[1] + red[2] + red[3];
}

// ------------------------------------------------------- K3: final loss
__global__ __launch_bounds__(256) void loss_kernel(
    const float* __restrict__ partials, int n, float* __restrict__ loss_out) {
    __shared__ float red[4];
    const int t = threadIdx.x;
    float s = 0.f;
    for (int i = t; i < n; i += 256) s += partials[i];
    #pragma unroll
    for (int off = 32; off >= 1; off >>= 1) s += __shfl_xor(s, off);
    if ((t & 63) == 0) red[t >> 6] = s;
    __syncthreads();
    if (t == 0) {
        float tot = red[0] + red[1] + red[2] + red[3];
        float m = tot / (float)(NTOK * DIM);
        loss_out[0] = m + 0.25f * m;
    }
}

extern "C" void kernel_launch(void* const* d_in, const int* in_sizes, int n_in,
                              void* d_out, int out_size, void* d_ws, size_t ws_size,
                              hipStream_t stream) {
    const float* z = (const float*)d_in[0];       // [131072, 64] f32
    const float* E = (const float*)d_in[1];       // [1024, 64] f32
    float* out = (float*)d_out;

    char* wsb = (char*)d_ws;
    float*          esq      = (float*)(wsb);              // 4 KB
    float*          esqh     = (float*)(wsb + 4096);       // 4 KB
    float*          partials = (float*)(wsb + 8192);       // 32 KB
    int*            cnt      = (int*)(wsb + 40960);        // 4 KB region
    int*            wl       = (int*)(wsb + 45056);        // 512 KB
    unsigned short* Bsp      = (unsigned short*)(wsb + 45056 + 524288); // 256 KB

    clear_kernel<<<1, 64, 0, stream>>>(cnt);
    esq_kernel<<<4, 256, 0, stream>>>(E, esq, esqh);
    bsplit_kernel<<<256, 256, 0, stream>>>(E, Bsp);
    mfma_argmin_kernel<<<NTOK / BM, 256, 0, stream>>>(z, Bsp, esqh,
                                                      out + IDX_OFF, cnt, wl);
    fallback_kernel<<<256, 256, 0, stream>>>(z, E, esq, out + IDX_OFF, wl, cnt);
    gather_kernel<<<NTOK / 16, 256, 0, stream>>>(z, E, out + IDX_OFF, out, partials);
    loss_kernel<<<1, 256, 0, stream>>>(partials, NTOK / 16, out + LOSS_OFF);
}

// Round 6
// 180.880 us; speedup vs baseline: 3.1286x; 1.3031x over previous
//
#include <hip/hip_runtime.h>

#define NTOK   131072
#define KCODES 1024
#define DIM    64
#define BM     128

#define LOSS_OFF (NTOK * DIM)        // 8388608
#define IDX_OFF  (LOSS_OFF + 1)      // 8388609

#define EPS_U 6e-5f                  // u-metric gap threshold (d-gap = 2u)

typedef __attribute__((ext_vector_type(8))) short bf16x8;
typedef __attribute__((ext_vector_type(4))) float f32x4;
typedef __attribute__((ext_vector_type(4))) unsigned short ush4;

__device__ inline unsigned short bf16rtn(float x) {
    unsigned u = __float_as_uint(x);
    return (unsigned short)((u + 0x7fffu + ((u >> 16) & 1u)) >> 16);
}

// ---------------------------------------------- K0a: e_sq (+ half) + clear cnt
__global__ __launch_bounds__(256) void esq_kernel(const float* __restrict__ E,
                                                  float* __restrict__ esq,
                                                  float* __restrict__ esqh,
                                                  int* __restrict__ cnt) {
    if (blockIdx.x == 0 && threadIdx.x == 0) cnt[0] = 0;
    int c = blockIdx.x * blockDim.x + threadIdx.x;
    if (c < KCODES) {
        const float4* row = (const float4*)(E + c * DIM);
        float s = 0.f;
        #pragma unroll
        for (int i = 0; i < DIM / 4; ++i) {
            float4 v = row[i];
            s += v.x * v.x + v.y * v.y + v.z * v.z + v.w * v.w;
        }
        esq[c] = s;
        esqh[c] = 0.5f * s;          // exact
    }
}

// ---------------------------------------------- K0b: split E -> bf16 hi|lo
__global__ __launch_bounds__(256) void bsplit_kernel(const float* __restrict__ E,
                                                     unsigned short* __restrict__ B) {
    int id = blockIdx.x * 256 + threadIdx.x;   // 65536 = 1024 x 64
    int c = id >> 6, k = id & 63;
    float x = E[id];
    unsigned short h = bf16rtn(x);
    float hf = __uint_as_float(((unsigned)h) << 16);
    unsigned short lo = bf16rtn(x - hf);
    B[c * 128 + k]      = h;
    B[c * 128 + 64 + k] = lo;
}

// ------------------------------------------------- K1: MFMA distances + argmin
// 512 threads = 8 waves as 4 row-groups x 2 col-groups; wave tile 32 tok x 64
// codes (fr=2 x fc=4 16x16 frags). K=192 bf16 (hh,hl,lh split). B tiles
// reg-prefetched (issue-early/write-late). u = esq/2 - dot; (best,second,idx)
// per token; cross-wave col combine via LDS; near-ties -> worklist.
__global__ __launch_bounds__(512, 4) void mfma_argmin_kernel(
    const float* __restrict__ z, const unsigned short* __restrict__ Bsp,
    const float* __restrict__ esqh_g, float* __restrict__ idx_out,
    int* __restrict__ cnt, int* __restrict__ wl) {
    __shared__ __align__(16) unsigned short As[16384];   // 32KB [128 tok][128 k-b]
    __shared__ __align__(16) unsigned short Bs[16384];   // 32KB [128 code][128 k-b]
    __shared__ __align__(16) float esqh_s[KCODES];       // 4KB
    __shared__ float cb_best[2][BM];                     // 1KB
    __shared__ float cb_sec[2][BM];                      // 1KB
    __shared__ int   cb_idx[2][BM];                      // 1KB

    char* AsB = (char*)As;
    char* BsB = (char*)Bs;

    const int t = threadIdx.x;
    const int l = t & 63;
    const int w = t >> 6;            // wave 0..7
    const int rg = w >> 1;           // row group (32 tokens)
    const int cg = w & 1;            // col group (64 codes)
    const int lan15 = l & 15;
    const int kp16 = (l >> 4) * 16;  // k-group byte offset within fragment
    const int xr = (lan15 & 7) << 4; // bank-swizzle XOR (row%8 == lan15%8)
    const int row0 = blockIdx.x * BM;

    // stage esq_half
    #pragma unroll
    for (int p = 0; p < 2; ++p) esqh_s[p * 512 + t] = esqh_g[p * 512 + t];

    // ---- prologue: load z tile + B tile 0, convert/write A, write B ----
    float4 av[4];
    {
        const float4* zg = (const float4*)(z + (size_t)row0 * DIM);
        #pragma unroll
        for (int p = 0; p < 4; ++p) av[p] = zg[p * 512 + t];
    }
    uint4 pv[4];
    {
        const uint4* bg = (const uint4*)Bsp;
        #pragma unroll
        for (int p = 0; p < 4; ++p) pv[p] = bg[p * 512 + t];
    }
    #pragma unroll
    for (int p = 0; p < 4; ++p) {
        int li = p * 512 + t;
        int r = li >> 4, q = li & 15;          // token row, float4 chunk
        float xs[4] = {av[p].x, av[p].y, av[p].z, av[p].w};
        ush4 hv, lv;
        #pragma unroll
        for (int j = 0; j < 4; ++j) {
            unsigned short h = bf16rtn(xs[j]);
            float hf = __uint_as_float(((unsigned)h) << 16);
            hv[j] = h;
            lv[j] = bf16rtn(xs[j] - hf);
        }
        int rx = (r & 7) << 4;
        *(ush4*)(AsB + r * 256 + ((q * 8) ^ rx))       = hv;
        *(ush4*)(AsB + r * 256 + ((128 + q * 8) ^ rx)) = lv;
    }
    #pragma unroll
    for (int p = 0; p < 4; ++p) {
        int li = p * 512 + t;
        int r = li >> 4, q = li & 15;
        *(uint4*)(BsB + r * 256 + ((q * 16) ^ ((r & 7) << 4))) = pv[p];
    }
    __syncthreads();

    // fragment addressing: base + compile-time frag offset + k-offset
    const int abase = (rg * 32 + lan15) * 256;   // + fr*4096 (const)
    const int bbase = (cg * 64 + lan15) * 256;   // + fc*4096 (const)
    int kofs[4];
    #pragma unroll
    for (int j = 0; j < 4; ++j) kofs[j] = (j * 64 + kp16) ^ xr;
    // split-term schedule: (A-half, B-half) quarters of 64 bytes
    const int jA[6] = {0, 1, 0, 1, 2, 3};        // hi,hi,hi,hi,lo,lo
    const int jB[6] = {0, 1, 2, 3, 0, 1};        // hi,hi,lo,lo,hi,hi

    float best[8], second[8];
    int   bidx[8];
    #pragma unroll
    for (int s = 0; s < 8; ++s) { best[s] = 3.4e38f; second[s] = 3.4e38f; bidx[s] = 0; }

    for (int ct = 0; ct < 8; ++ct) {             // ascending code tiles
        uint4 pv2[4];
        if (ct < 7) {                            // issue-early next B tile
            const uint4* bg2 = (const uint4*)Bsp + (size_t)(ct + 1) * 2048;
            #pragma unroll
            for (int p = 0; p < 4; ++p) pv2[p] = bg2[p * 512 + t];
        }

        f32x4 acc[2][4];
        #pragma unroll
        for (int fr = 0; fr < 2; ++fr)
            #pragma unroll
            for (int fc = 0; fc < 4; ++fc)
                acc[fr][fc] = (f32x4){0.f, 0.f, 0.f, 0.f};

        #pragma unroll
        for (int ks = 0; ks < 6; ++ks) {
            bf16x8 af0 = *(const bf16x8*)(AsB + abase +        kofs[jA[ks]]);
            bf16x8 af1 = *(const bf16x8*)(AsB + abase + 4096 + kofs[jA[ks]]);
            #pragma unroll
            for (int fc = 0; fc < 4; ++fc) {
                bf16x8 bf = *(const bf16x8*)(BsB + bbase + fc * 4096 + kofs[jB[ks]]);
                acc[0][fc] = __builtin_amdgcn_mfma_f32_16x16x32_bf16(
                    af0, bf, acc[0][fc], 0, 0, 0);
                acc[1][fc] = __builtin_amdgcn_mfma_f32_16x16x32_bf16(
                    af1, bf, acc[1][fc], 0, 0, 0);
            }
        }

        // epilogue: u = esq/2 - dot; branchless (best, second, idx)
        #pragma unroll
        for (int fc = 0; fc < 4; ++fc) {
            int col = ct * 128 + cg * 64 + fc * 16 + lan15;
            float eh = esqh_s[col];
            #pragma unroll
            for (int fr = 0; fr < 2; ++fr) {
                #pragma unroll
                for (int r = 0; r < 4; ++r) {
                    float u = eh - acc[fr][fc][r];
                    int s = fr * 4 + r;
                    second[s] = fminf(second[s], fmaxf(u, best[s]));
                    bidx[s] = (u < best[s]) ? col : bidx[s];
                    best[s] = fminf(u, best[s]);
                }
            }
        }
        __syncthreads();                          // done reading Bs
        if (ct < 7) {                             // write-late staging
            #pragma unroll
            for (int p = 0; p < 4; ++p) {
                int li = p * 512 + t;
                int r = li >> 4, q = li & 15;
                *(uint4*)(BsB + r * 256 + ((q * 16) ^ ((r & 7) << 4))) = pv2[p];
            }
        }
        __syncthreads();
    }

    // intra-wave reduce over 16-lane groups (lex: ties -> smaller col)
    #pragma unroll
    for (int s = 0; s < 8; ++s) {
        float b = best[s], sc = second[s];
        int bi = bidx[s];
        #pragma unroll
        for (int off = 1; off <= 8; off <<= 1) {
            float ob = __shfl_xor(b, off);
            float os = __shfl_xor(sc, off);
            int   oi = __shfl_xor(bi, off);
            float mx = fmaxf(b, ob);
            sc = fminf(fminf(sc, os), mx);
            if (ob < b) { b = ob; bi = oi; }
            else if (ob == b) bi = min(bi, oi);
        }
        best[s] = b; second[s] = sc; bidx[s] = bi;
    }
    if (lan15 == 0) {
        #pragma unroll
        for (int s = 0; s < 8; ++s) {
            int row = rg * 32 + (s >> 2) * 16 + (l >> 4) * 4 + (s & 3);
            cb_best[cg][row] = best[s];
            cb_sec[cg][row]  = second[s];
            cb_idx[cg][row]  = bidx[s];
        }
    }
    __syncthreads();
    // cross-wave (col-group) combine; each cg candidate is lex-min of its set
    if (t < BM) {
        float b0 = cb_best[0][t], b1 = cb_best[1][t];
        float s0 = cb_sec[0][t],  s1 = cb_sec[1][t];
        int   i0 = cb_idx[0][t],  i1 = cb_idx[1][t];
        float b; int bi;
        if (b1 < b0 || (b1 == b0 && i1 < i0)) { b = b1; bi = i1; }
        else                                  { b = b0; bi = i0; }
        float sec = fminf(fminf(s0, s1), fmaxf(b0, b1));
        int gid = row0 + t;
        idx_out[gid] = (float)bi;
        if (sec - b <= EPS_U) {
            int slot = atomicAdd(cnt, 1);
            if (slot < NTOK) wl[slot] = gid;
        }
    }
}

// ---------------------- K1b: exact recompute for worklisted (near-tie) tokens
__global__ __launch_bounds__(256) void fallback_kernel(
    const float* __restrict__ z, const float* __restrict__ E,
    const float* __restrict__ esq_g, float* __restrict__ idx_out,
    const int* __restrict__ wl, const int* __restrict__ cnt_p) {
    __shared__ __align__(16) float es[DIM][128];   // 32KB [k][code]
    __shared__ __align__(16) float zl[16][72];     // padded
    __shared__ float zqs[16];

    const int t = threadIdx.x;
    const int tg = t >> 4;           // token slot 0..15
    const int cs = t & 15;           // code slice (8 codes per tile)
    const int cnt = min(*cnt_p, NTOK);

    for (int chunk = blockIdx.x; chunk * 16 < cnt; chunk += 256) {
        const int base = chunk * 16;
        const int nval = min(16, cnt - base);
        const int tok = wl[base + (tg < nval ? tg : 0)];
        {
            float4 v = ((const float4*)z)[(size_t)tok * 16 + cs];
            *(float4*)&zl[tg][cs * 4] = v;
        }
        __syncthreads();
        if (t < 16) {                // zq per slot, sequential k (as R1)
            float s = 0.f;
            for (int k = 0; k < DIM; ++k) { float v = zl[t][k]; s += v * v; }
            zqs[t] = s;
        }
        __syncthreads();
        const float zq = zqs[tg];

        float best = 3.4e38f;
        int bi = 0;
        for (int tile = 0; tile < 8; ++tile) {   // ascending code tiles
            const float4* eg = (const float4*)(E + (size_t)tile * 128 * DIM);
            #pragma unroll
            for (int p = 0; p < 8; ++p) {        // R2 staging pattern verbatim
                int li = p * 256 + t;
                int c = li & 127, k4 = li >> 7;
                float4 v = eg[c * 16 + k4];
                es[k4 * 4 + 0][c] = v.x;
                es[k4 * 4 + 1][c] = v.y;
                es[k4 * 4 + 2][c] = v.z;
                es[k4 * 4 + 3][c] = v.w;
            }
            __syncthreads();

            float acc[8];
            #pragma unroll
            for (int n = 0; n < 8; ++n) acc[n] = 0.f;
            #pragma unroll 8
            for (int k = 0; k < DIM; ++k) {      // sequential fp32 FMA over K
                float a = zl[tg][k];
                float4 b0 = *(const float4*)&es[k][cs * 8 + 0];
                float4 b1 = *(const float4*)&es[k][cs * 8 + 4];
                float b[8] = {b0.x, b0.y, b0.z, b0.w, b1.x, b1.y, b1.z, b1.w};
                #pragma unroll
                for (int n = 0; n < 8; ++n) acc[n] += a * b[n];
            }
            #pragma unroll
            for (int n = 0; n < 8; ++n) {        // ascending code index, strict <
                int c = tile * 128 + cs * 8 + n;
                float d = (zq - 2.0f * acc[n]) + esq_g[c];
                if (d < best) { best = d; bi = c; }
            }
            __syncthreads();
        }
        #pragma unroll
        for (int off = 1; off <= 8; off <<= 1) {
            float ob = __shfl_xor(best, off);
            int   oi = __shfl_xor(bi, off);
            if (ob < best || (ob == best && oi < bi)) { best = ob; bi = oi; }
        }
        if (cs == 0 && tg < nval) idx_out[tok] = (float)bi;
        __syncthreads();
    }
}

// ------------------------------- K2: gather z_q, write out0, loss partials
__global__ __launch_bounds__(256) void gather_kernel(
    const float* __restrict__ z, const float* __restrict__ E,
    const float* __restrict__ idx_f, float* __restrict__ out0,
    float* __restrict__ partials) {
    __shared__ float red[4];
    const int t = threadIdx.x;
    const int token = blockIdx.x * 16 + (t >> 4);
    const int part  = t & 15;

    int id = (int)idx_f[token];
    const float4* z4 = (const float4*)z;
    const float4* E4 = (const float4*)E;
    float4 zv = z4[(size_t)token * 16 + part];
    float4 ev = E4[(size_t)id * 16 + part];

    float dx = ev.x - zv.x, dy = ev.y - zv.y, dz = ev.z - zv.z, dw = ev.w - zv.w;
    float4 o;
    o.x = zv.x + dx; o.y = zv.y + dy; o.z = zv.z + dz; o.w = zv.w + dw;
    ((float4*)out0)[(size_t)token * 16 + part] = o;

    float ls = dx * dx + dy * dy + dz * dz + dw * dw;
    #pragma unroll
    for (int off = 32; off >= 1; off >>= 1) ls += __shfl_xor(ls, off);
    if ((t & 63) == 0) red[t >> 6] = ls;
    __syncthreads();
    if (t == 0) partials[blockIdx.x] = red[0] + red[1] + red[2] + red[3];
}

// ------------------------------------------------------- K3: final loss
__global__ __launch_bounds__(256) void loss_kernel(
    const float* __restrict__ partials, int n, float* __restrict__ loss_out) {
    __shared__ float red[4];
    const int t = threadIdx.x;
    float s = 0.f;
    for (int i = t; i < n; i += 256) s += partials[i];
    #pragma unroll
    for (int off = 32; off >= 1; off >>= 1) s += __shfl_xor(s, off);
    if ((t & 63) == 0) red[t >> 6] = s;
    __syncthreads();
    if (t == 0) {
        float tot = red[0] + red[1] + red[2] + red[3];
        float m = tot / (float)(NTOK * DIM);
        loss_out[0] = m + 0.25f * m;
    }
}

extern "C" void kernel_launch(void* const* d_in, const int* in_sizes, int n_in,
                              void* d_out, int out_size, void* d_ws, size_t ws_size,
                              hipStream_t stream) {
    const float* z = (const float*)d_in[0];       // [131072, 64] f32
    const float* E = (const float*)d_in[1];       // [1024, 64] f32
    float* out = (float*)d_out;

    char* wsb = (char*)d_ws;
    float*          esq      = (float*)(wsb);              // 4 KB
    float*          esqh     = (float*)(wsb + 4096);       // 4 KB
    float*          partials = (float*)(wsb + 8192);       // 32 KB
    int*            cnt      = (int*)(wsb + 40960);        // 4 KB region
    int*            wl       = (int*)(wsb + 45056);        // 512 KB
    unsigned short* Bsp      = (unsigned short*)(wsb + 45056 + 524288); // 256 KB

    esq_kernel<<<4, 256, 0, stream>>>(E, esq, esqh, cnt);
    bsplit_kernel<<<256, 256, 0, stream>>>(E, Bsp);
    mfma_argmin_kernel<<<NTOK / BM, 512, 0, stream>>>(z, Bsp, esqh,
                                                      out + IDX_OFF, cnt, wl);
    fallback_kernel<<<256, 256, 0, stream>>>(z, E, esq, out + IDX_OFF, wl, cnt);
    gather_kernel<<<NTOK / 16, 256, 0, stream>>>(z, E, out + IDX_OFF, out, partials);
    loss_kernel<<<1, 256, 0, stream>>>(partials, NTOK / 16, out + LOSS_OFF);
}

// Round 7
// 175.297 us; speedup vs baseline: 3.2283x; 1.0318x over previous
//
#include <hip/hip_runtime.h>

#define NTOK   131072
#define KCODES 1024
#define DIM    64
#define BM     128
#define BN     64
#define NCT    (KCODES / BN)         // 16 code tiles

#define LOSS_OFF (NTOK * DIM)        // 8388608
#define IDX_OFF  (LOSS_OFF + 1)      // 8388609

#define EPS_U 6e-5f                  // u-metric gap threshold (d-gap = 2u)

typedef __attribute__((ext_vector_type(8))) short bf16x8;
typedef __attribute__((ext_vector_type(4))) float f32x4;
typedef __attribute__((ext_vector_type(4))) unsigned short ush4;

__device__ inline unsigned short bf16rtn(float x) {
    unsigned u = __float_as_uint(x);
    return (unsigned short)((u + 0x7fffu + ((u >> 16) & 1u)) >> 16);
}

// -------------------- K0: split E -> bf16 hi|lo, esq(+half), clear cnt
__global__ __launch_bounds__(256) void prep_kernel(const float* __restrict__ E,
                                                   unsigned short* __restrict__ B,
                                                   float* __restrict__ esq,
                                                   float* __restrict__ esqh,
                                                   int* __restrict__ cnt) {
    const int t = threadIdx.x, b = blockIdx.x;
    if (b == 0 && t == 0) cnt[0] = 0;
    int id = b * 256 + t;                      // 65536 = 1024 x 64
    int c = id >> 6, k = id & 63;
    float x = E[id];
    unsigned short h = bf16rtn(x);
    float hf = __uint_as_float(((unsigned)h) << 16);
    unsigned short lo = bf16rtn(x - hf);
    B[c * 128 + k]      = h;
    B[c * 128 + 64 + k] = lo;
    if (b < 4) {                               // esq: arithmetic verbatim (R1-R6)
        int cc = b * 256 + t;
        const float4* row = (const float4*)(E + cc * DIM);
        float s = 0.f;
        #pragma unroll
        for (int i = 0; i < DIM / 4; ++i) {
            float4 v = row[i];
            s += v.x * v.x + v.y * v.y + v.z * v.z + v.w * v.w;
        }
        esq[cc] = s;
        esqh[cc] = 0.5f * s;                   // exact
    }
}

// ------------------------------------------------- K1: MFMA distances + argmin
// 512 threads = 8 waves as 4 row-groups x 2 col-groups; wave tile 32 tok x 32
// codes (fr=2 x fc=2 16x16 frags), 16 code tiles of BN=64. K=192 bf16
// (hh,hl,lh). A frags ct-invariant -> preloaded to regs; B hi-frags reused
// within ct (read 4, use 6). B tiles reg-prefetched, write-late.
__global__ __launch_bounds__(512, 4) void mfma_argmin_kernel(
    const float* __restrict__ z, const unsigned short* __restrict__ Bsp,
    const float* __restrict__ esqh_g, float* __restrict__ idx_out,
    int* __restrict__ cnt, int* __restrict__ wl) {
    __shared__ __align__(16) unsigned short As[16384];   // 32KB [128 tok][256B k]
    __shared__ __align__(16) unsigned short Bs[8192];    // 16KB [64 code][256B k]
    __shared__ __align__(16) float esqh_s[KCODES];       // 4KB
    __shared__ float cb_best[2][BM];                     // 1KB
    __shared__ float cb_sec[2][BM];                      // 1KB
    __shared__ int   cb_idx[2][BM];                      // 1KB

    char* AsB = (char*)As;
    char* BsB = (char*)Bs;

    const int t = threadIdx.x;
    const int l = t & 63;
    const int w = t >> 6;            // wave 0..7
    const int rg = w >> 1;           // row group (32 tokens)
    const int cg = w & 1;            // col group (32 codes)
    const int lan15 = l & 15;
    const int kp16 = (l >> 4) * 16;  // k-group byte offset within fragment
    const int xr = (lan15 & 7) << 4; // bank-swizzle XOR (row%8 == lan15%8)
    const int row0 = blockIdx.x * BM;

    // stage esq_half
    #pragma unroll
    for (int p = 0; p < 2; ++p) esqh_s[p * 512 + t] = esqh_g[p * 512 + t];

    // ---- prologue: load z tile + B tile 0, convert/write A, write B ----
    float4 av[4];
    {
        const float4* zg = (const float4*)(z + (size_t)row0 * DIM);
        #pragma unroll
        for (int p = 0; p < 4; ++p) av[p] = zg[p * 512 + t];
    }
    uint4 pv[2];
    {
        const uint4* bg = (const uint4*)Bsp;
        #pragma unroll
        for (int p = 0; p < 2; ++p) pv[p] = bg[p * 512 + t];
    }
    #pragma unroll
    for (int p = 0; p < 4; ++p) {
        int li = p * 512 + t;
        int r = li >> 4, q = li & 15;          // token row, float4 chunk
        float xs[4] = {av[p].x, av[p].y, av[p].z, av[p].w};
        ush4 hv, lv;
        #pragma unroll
        for (int j = 0; j < 4; ++j) {
            unsigned short h = bf16rtn(xs[j]);
            float hf = __uint_as_float(((unsigned)h) << 16);
            hv[j] = h;
            lv[j] = bf16rtn(xs[j] - hf);
        }
        int rx = (r & 7) << 4;
        *(ush4*)(AsB + r * 256 + ((q * 8) ^ rx))       = hv;
        *(ush4*)(AsB + r * 256 + ((128 + q * 8) ^ rx)) = lv;
    }
    #pragma unroll
    for (int p = 0; p < 2; ++p) {
        int li = p * 512 + t;
        int r = li >> 4, q = li & 15;
        *(uint4*)(BsB + r * 256 + ((q * 16) ^ ((r & 7) << 4))) = pv[p];
    }
    __syncthreads();

    // k-offsets for the 4 64B quarters (hi k0-31, hi k32-63, lo k0-31, lo k32-63)
    int kofs[4];
    #pragma unroll
    for (int j = 0; j < 4; ++j) kofs[j] = (j * 64 + kp16) ^ xr;

    // A fragments are code-tile invariant: preload all 2fr x 4j into regs
    const int abase = (rg * 32 + lan15) * 256;
    bf16x8 afr[2][4];
    #pragma unroll
    for (int fr = 0; fr < 2; ++fr)
        #pragma unroll
        for (int j = 0; j < 4; ++j)
            afr[fr][j] = *(const bf16x8*)(AsB + abase + fr * 4096 + kofs[j]);

    const int bbase = (cg * 32 + lan15) * 256;   // + fc*4096 (const)

    float best[8], second[8];
    int   bidx[8];
    #pragma unroll
    for (int s = 0; s < 8; ++s) { best[s] = 3.4e38f; second[s] = 3.4e38f; bidx[s] = 0; }

    for (int ct = 0; ct < NCT; ++ct) {           // ascending code tiles
        uint4 pv2[2];
        if (ct < NCT - 1) {                      // issue-early next B tile
            const uint4* bg2 = (const uint4*)Bsp + (size_t)(ct + 1) * 1024;
            #pragma unroll
            for (int p = 0; p < 2; ++p) pv2[p] = bg2[p * 512 + t];
        }

        f32x4 acc[2][2];
        #pragma unroll
        for (int fr = 0; fr < 2; ++fr)
            #pragma unroll
            for (int fc = 0; fc < 2; ++fc)
                acc[fr][fc] = (f32x4){0.f, 0.f, 0.f, 0.f};

        // term order per acc (FP-identical to R6): hh(k0),hh(k1),hl(k0),hl(k1),
        // lh(k0),lh(k1); B-hi frags b0,b1 read once, reused for lh.
        #pragma unroll
        for (int fc = 0; fc < 2; ++fc) {
            const char* bp = BsB + bbase + fc * 4096;
            bf16x8 b0 = *(const bf16x8*)(bp + kofs[0]);
            bf16x8 b1 = *(const bf16x8*)(bp + kofs[1]);
            acc[0][fc] = __builtin_amdgcn_mfma_f32_16x16x32_bf16(afr[0][0], b0, acc[0][fc], 0, 0, 0);
            acc[1][fc] = __builtin_amdgcn_mfma_f32_16x16x32_bf16(afr[1][0], b0, acc[1][fc], 0, 0, 0);
            acc[0][fc] = __builtin_amdgcn_mfma_f32_16x16x32_bf16(afr[0][1], b1, acc[0][fc], 0, 0, 0);
            acc[1][fc] = __builtin_amdgcn_mfma_f32_16x16x32_bf16(afr[1][1], b1, acc[1][fc], 0, 0, 0);
            bf16x8 b2 = *(const bf16x8*)(bp + kofs[2]);
            acc[0][fc] = __builtin_amdgcn_mfma_f32_16x16x32_bf16(afr[0][0], b2, acc[0][fc], 0, 0, 0);
            acc[1][fc] = __builtin_amdgcn_mfma_f32_16x16x32_bf16(afr[1][0], b2, acc[1][fc], 0, 0, 0);
            bf16x8 b3 = *(const bf16x8*)(bp + kofs[3]);
            acc[0][fc] = __builtin_amdgcn_mfma_f32_16x16x32_bf16(afr[0][1], b3, acc[0][fc], 0, 0, 0);
            acc[1][fc] = __builtin_amdgcn_mfma_f32_16x16x32_bf16(afr[1][1], b3, acc[1][fc], 0, 0, 0);
            acc[0][fc] = __builtin_amdgcn_mfma_f32_16x16x32_bf16(afr[0][2], b0, acc[0][fc], 0, 0, 0);
            acc[1][fc] = __builtin_amdgcn_mfma_f32_16x16x32_bf16(afr[1][2], b0, acc[1][fc], 0, 0, 0);
            acc[0][fc] = __builtin_amdgcn_mfma_f32_16x16x32_bf16(afr[0][3], b1, acc[0][fc], 0, 0, 0);
            acc[1][fc] = __builtin_amdgcn_mfma_f32_16x16x32_bf16(afr[1][3], b1, acc[1][fc], 0, 0, 0);
        }

        // epilogue: u = esq/2 - dot; branchless (best, second, idx)
        #pragma unroll
        for (int fc = 0; fc < 2; ++fc) {
            int col = ct * BN + cg * 32 + fc * 16 + lan15;
            float eh = esqh_s[col];
            #pragma unroll
            for (int fr = 0; fr < 2; ++fr) {
                #pragma unroll
                for (int r = 0; r < 4; ++r) {
                    float u = eh - acc[fr][fc][r];
                    int s = fr * 4 + r;
                    second[s] = fminf(second[s], fmaxf(u, best[s]));
                    bidx[s] = (u < best[s]) ? col : bidx[s];
                    best[s] = fminf(u, best[s]);
                }
            }
        }
        __syncthreads();                          // done reading Bs
        if (ct < NCT - 1) {                       // write-late staging
            #pragma unroll
            for (int p = 0; p < 2; ++p) {
                int li = p * 512 + t;
                int r = li >> 4, q = li & 15;
                *(uint4*)(BsB + r * 256 + ((q * 16) ^ ((r & 7) << 4))) = pv2[p];
            }
        }
        __syncthreads();
    }

    // intra-wave reduce over 16-lane groups (lex: ties -> smaller col)
    #pragma unroll
    for (int s = 0; s < 8; ++s) {
        float b = best[s], sc = second[s];
        int bi = bidx[s];
        #pragma unroll
        for (int off = 1; off <= 8; off <<= 1) {
            float ob = __shfl_xor(b, off);
            float os = __shfl_xor(sc, off);
            int   oi = __shfl_xor(bi, off);
            float mx = fmaxf(b, ob);
            sc = fminf(fminf(sc, os), mx);
            if (ob < b) { b = ob; bi = oi; }
            else if (ob == b) bi = min(bi, oi);
        }
        best[s] = b; second[s] = sc; bidx[s] = bi;
    }
    if (lan15 == 0) {
        #pragma unroll
        for (int s = 0; s < 8; ++s) {
            int row = rg * 32 + (s >> 2) * 16 + (l >> 4) * 4 + (s & 3);
            cb_best[cg][row] = best[s];
            cb_sec[cg][row]  = second[s];
            cb_idx[cg][row]  = bidx[s];
        }
    }
    __syncthreads();
    // cross-wave (col-group) combine; each cg candidate is lex-min of its set
    if (t < BM) {
        float b0 = cb_best[0][t], b1 = cb_best[1][t];
        float s0 = cb_sec[0][t],  s1 = cb_sec[1][t];
        int   i0 = cb_idx[0][t],  i1 = cb_idx[1][t];
        float b; int bi;
        if (b1 < b0 || (b1 == b0 && i1 < i0)) { b = b1; bi = i1; }
        else                                  { b = b0; bi = i0; }
        float sec = fminf(fminf(s0, s1), fmaxf(b0, b1));
        int gid = row0 + t;
        idx_out[gid] = (float)bi;
        if (sec - b <= EPS_U) {
            int slot = atomicAdd(cnt, 1);
            if (slot < NTOK) wl[slot] = gid;
        }
    }
}

// ---------------------- K1b: exact recompute for worklisted (near-tie) tokens
__global__ __launch_bounds__(256) void fallback_kernel(
    const float* __restrict__ z, const float* __restrict__ E,
    const float* __restrict__ esq_g, float* __restrict__ idx_out,
    const int* __restrict__ wl, const int* __restrict__ cnt_p) {
    __shared__ __align__(16) float es[DIM][128];   // 32KB [k][code]
    __shared__ __align__(16) float zl[16][72];     // padded
    __shared__ float zqs[16];

    const int t = threadIdx.x;
    const int tg = t >> 4;           // token slot 0..15
    const int cs = t & 15;           // code slice (8 codes per tile)
    const int cnt = min(*cnt_p, NTOK);

    for (int chunk = blockIdx.x; chunk * 16 < cnt; chunk += 256) {
        const int base = chunk * 16;
        const int nval = min(16, cnt - base);
        const int tok = wl[base + (tg < nval ? tg : 0)];
        {
            float4 v = ((const float4*)z)[(size_t)tok * 16 + cs];
            *(float4*)&zl[tg][cs * 4] = v;
        }
        __syncthreads();
        if (t < 16) {                // zq per slot, sequential k (as R1)
            float s = 0.f;
            for (int k = 0; k < DIM; ++k) { float v = zl[t][k]; s += v * v; }
            zqs[t] = s;
        }
        __syncthreads();
        const float zq = zqs[tg];

        float best = 3.4e38f;
        int bi = 0;
        for (int tile = 0; tile < 8; ++tile) {   // ascending code tiles
            const float4* eg = (const float4*)(E + (size_t)tile * 128 * DIM);
            #pragma unroll
            for (int p = 0; p < 8; ++p) {        // R2 staging pattern verbatim
                int li = p * 256 + t;
                int c = li & 127, k4 = li >> 7;
                float4 v = eg[c * 16 + k4];
                es[k4 * 4 + 0][c] = v.x;
                es[k4 * 4 + 1][c] = v.y;
                es[k4 * 4 + 2][c] = v.z;
                es[k4 * 4 + 3][c] = v.w;
            }
            __syncthreads();

            float acc[8];
            #pragma unroll
            for (int n = 0; n < 8; ++n) acc[n] = 0.f;
            #pragma unroll 8
            for (int k = 0; k < DIM; ++k) {      // sequential fp32 FMA over K
                float a = zl[tg][k];
                float4 b0 = *(const float4*)&es[k][cs * 8 + 0];
                float4 b1 = *(const float4*)&es[k][cs * 8 + 4];
                float b[8] = {b0.x, b0.y, b0.z, b0.w, b1.x, b1.y, b1.z, b1.w};
                #pragma unroll
                for (int n = 0; n < 8; ++n) acc[n] += a * b[n];
            }
            #pragma unroll
            for (int n = 0; n < 8; ++n) {        // ascending code index, strict <
                int c = tile * 128 + cs * 8 + n;
                float d = (zq - 2.0f * acc[n]) + esq_g[c];
                if (d < best) { best = d; bi = c; }
            }
            __syncthreads();
        }
        #pragma unroll
        for (int off = 1; off <= 8; off <<= 1) {
            float ob = __shfl_xor(best, off);
            int   oi = __shfl_xor(bi, off);
            if (ob < best || (ob == best && oi < bi)) { best = ob; bi = oi; }
        }
        if (cs == 0 && tg < nval) idx_out[tok] = (float)bi;
        __syncthreads();
    }
}

// ------------------------------- K2: gather z_q, write out0, loss partials
__global__ __launch_bounds__(256) void gather_kernel(
    const float* __restrict__ z, const float* __restrict__ E,
    const float* __restrict__ idx_f, float* __restrict__ out0,
    float* __restrict__ partials) {
    __shared__ float red[4];
    const int t = threadIdx.x;
    const int token = blockIdx.x * 16 + (t >> 4);
    const int part  = t & 15;

    int id = (int)idx_f[token];
    const float4* z4 = (const float4*)z;
    const float4* E4 = (const float4*)E;
    float4 zv = z4[(size_t)token * 16 + part];
    float4 ev = E4[(size_t)id * 16 + part];

    float dx = ev.x - zv.x, dy = ev.y - zv.y, dz = ev.z - zv.z, dw = ev.w - zv.w;
    float4 o;
    o.x = zv.x + dx; o.y = zv.y + dy; o.z = zv.z + dz; o.w = zv.w + dw;
    ((float4*)out0)[(size_t)token * 16 + part] = o;

    float ls = dx * dx + dy * dy + dz * dz + dw * dw;
    #pragma unroll
    for (int off = 32; off >= 1; off >>= 1) ls += __shfl_xor(ls, off);
    if ((t & 63) == 0) red[t >> 6] = ls;
    __syncthreads();
    if (t == 0) partials[blockIdx.x] = red[0] + red[1] + red[2] + red[3];
}

// ------------------------------------------------------- K3: final loss
__global__ __launch_bounds__(256) void loss_kernel(
    const float* __restrict__ partials, int n, float* __restrict__ loss_out) {
    __shared__ float red[4];
    const int t = threadIdx.x;
    float s = 0.f;
    for (int i = t; i < n; i += 256) s += partials[i];
    #pragma unroll
    for (int off = 32; off >= 1; off >>= 1) s += __shfl_xor(s, off);
    if ((t & 63) == 0) red[t >> 6] = s;
    __syncthreads();
    if (t == 0) {
        float tot = red[0] + red[1] + red[2] + red[3];
        float m = tot / (float)(NTOK * DIM);
        loss_out[0] = m + 0.25f * m;
    }
}

extern "C" void kernel_launch(void* const* d_in, const int* in_sizes, int n_in,
                              void* d_out, int out_size, void* d_ws, size_t ws_size,
                              hipStream_t stream) {
    const float* z = (const float*)d_in[0];       // [131072, 64] f32
    const float* E = (const float*)d_in[1];       // [1024, 64] f32
    float* out = (float*)d_out;

    char* wsb = (char*)d_ws;
    float*          esq      = (float*)(wsb);              // 4 KB
    float*          esqh     = (float*)(wsb + 4096);       // 4 KB
    float*          partials = (float*)(wsb + 8192);       // 32 KB
    int*            cnt      = (int*)(wsb + 40960);        // 4 KB region
    int*            wl       = (int*)(wsb + 45056);        // 512 KB
    unsigned short* Bsp      = (unsigned short*)(wsb + 45056 + 524288); // 256 KB

    prep_kernel<<<256, 256, 0, stream>>>(E, Bsp, esq, esqh, cnt);
    mfma_argmin_kernel<<<NTOK / BM, 512, 0, stream>>>(z, Bsp, esqh,
                                                      out + IDX_OFF, cnt, wl);
    fallback_kernel<<<256, 256, 0, stream>>>(z, E, esq, out + IDX_OFF, wl, cnt);
    gather_kernel<<<NTOK / 16, 256, 0, stream>>>(z, E, out + IDX_OFF, out, partials);
    loss_kernel<<<1, 256, 0, stream>>>(partials, NTOK / 16, out + LOSS_OFF);
}